// Round 7
// baseline (169.249 us; speedup 1.0000x reference)
//
#include <hip/hip_runtime.h>
#include <hip/hip_cooperative_groups.h>
#include <hip/hip_bf16.h>

namespace cg = cooperative_groups;

// Problem constants (from reference)
#define Bg 64       // graphs
#define Nn 256      // nodes per subgraph
#define Ee 2048     // edges per subgraph
#define Dd 128      // hidden dim
#define Hh 4        // heads
#define MAXJ 40     // cap on in-edges of node 0 (+self) per layer; Binom(2048,1/256): P(>38)~1e-17
#define RS 132      // LDS row stride (128 + 4 pad)

__device__ __forceinline__ float bf2f(unsigned short u) {
    return __uint_as_float(((unsigned)u) << 16);
}

// ---------------------------------------------------------------------------
// ONE cooperative dispatch, 128 blocks x 256 threads; block x -> (b=x&63,
// l=x>>6). Blocks 0..23 fold one wv row each; 24,25 fold bdot. All blocks
// overlap that with their own edge-scan/gather (independent of wv). grid.sync
// provides device-scope release/acquire, so wv/partial cross-block reads are
// plain vector loads (no spin flags, no atomic-load staging — round 5's sin).
//   wv row r = l*12 + t*4 + h: wv[r][k] = sum_d av_t[d] * W_l[h*Dd+d, k]
//     t: 0=att_src, 1=att_dst, 2=mlp half
// ---------------------------------------------------------------------------
__global__ __launch_bounds__(256) void gat_coop_kernel(
    const int* nn1, const int* nn2, const int* adj1, const int* adj2,
    const void* emb,
    const void* W1, const void* as1, const void* ad1, const void* b1,
    const void* W2, const void* as2, const void* ad2, const void* b2,
    const void* mlpw, const void* mlpb,
    float* wvg,       // [24*128] + [2] bdot at 3072,3073
    float* partial,   // [128], indexed by block id
    void* out)
{
    cg::grid_group grid = cg::this_grid();

    __shared__ float s_av[Dd];
    __shared__ float s_half[256];
    __shared__ float s_wv[12 * RS];          // 6.3 KB
    __shared__ float s_rows[MAXJ * RS];      // 21.1 KB
    __shared__ int   s_srcj[MAXJ];
    __shared__ int   s_gid[MAXJ];
    __shared__ int   s_cnt, s_f32;
    __shared__ float s_ps[MAXJ * Hh], s_pm[MAXJ * Hh];
    __shared__ float s_pd[Hh], s_hval[Hh], s_bd;

    const int tid = threadIdx.x;
    const int x = blockIdx.x;
    const int b = x & (Bg - 1);
    const int l = x >> 6;

    if (tid == 0) { s_f32 = 0; s_cnt = 0; }
    __syncthreads();
    // dtype probe: fp32 read as bf16 halfwords -> |x|>64 or NaN w.p. ~0.5 per
    // low halfword; true bf16 weights are all |x| < 0.3.
    {
        float v = __bfloat162float(((const __hip_bfloat16*)W1)[tid]);
        if (!(v > -64.f && v < 64.f)) atomicOr(&s_f32, 1);
    }
    __syncthreads();
    const int f32 = s_f32;

    // ---- Phase 1a: fold (blocks 0..23) / bdot (24,25). Block-uniform branch.
    if (x < 24) {
        const int pl = x / 12;
        const int t  = (x % 12) >> 2;
        const int h  = x & 3;
        const void* avp; long off;
        if (t == 0)      { avp = pl ? as2 : as1; off = (long)h * Dd; }
        else if (t == 1) { avp = pl ? ad2 : ad1; off = (long)h * Dd; }
        else             { avp = mlpw;           off = (long)pl * Dd; }
        if (tid < Dd)
            s_av[tid] = f32 ? ((const float*)avp)[off + tid]
                            : bf2f(((const unsigned short*)avp)[off + tid]);
        __syncthreads();
        {   // split-d: thread k sums d in [0,64), thread k+128 sums [64,128)
            const int k  = tid & 127;
            const int d0 = (tid >> 7) * 64;
            float acc = 0.f;
            if (f32) {
                const float* Wf = (const float*)(pl ? W2 : W1)
                                + ((long)h * Dd + d0) * Dd + k;
                #pragma unroll 8
                for (int d = 0; d < 64; ++d) acc += s_av[d0 + d] * Wf[(long)d * Dd];
            } else {
                const unsigned short* Wb = (const unsigned short*)(pl ? W2 : W1)
                                         + ((long)h * Dd + d0) * Dd + k;
                #pragma unroll 8
                for (int d = 0; d < 64; ++d) acc += s_av[d0 + d] * bf2f(Wb[(long)d * Dd]);
            }
            s_half[tid] = acc;
        }
        __syncthreads();
        if (tid < Dd) wvg[x * Dd + tid] = s_half[tid] + s_half[tid + 128];
    } else if (x < 26) {
        const int pl = x - 24;
        if (tid < Dd) {
            const void* bias = pl ? b2 : b1;
            float bv = f32 ? ((const float*)bias)[tid]
                           : bf2f(((const unsigned short*)bias)[tid]);
            float mv = f32 ? ((const float*)mlpw)[pl * Dd + tid]
                           : bf2f(((const unsigned short*)mlpw)[pl * Dd + tid]);
            s_half[tid] = bv * mv;
        }
        __syncthreads();
        for (int s = 64; s > 0; s >>= 1) {
            if (tid < s) s_half[tid] += s_half[tid + s];
            __syncthreads();
        }
        if (tid == 0) {
            float a = s_half[0];
            if (pl == 0)
                a += f32 ? ((const float*)mlpb)[0]
                         : bf2f(((const unsigned short*)mlpb)[0]);
            wvg[3072 + pl] = a;
        }
    }

    // ---- Phase 1b: edge scan + gather for (b,l) — independent of wv.
    const int* adjp = (l ? adj2 : adj1) + (long)b * 2 * Ee;
    const int* dstp = adjp + Ee;
    for (int i = tid; i < Ee / 4; i += 256) {
        int4 d4 = ((const int4*)dstp)[i];
        int base = i * 4;
        if (d4.x == 0) { int p = atomicAdd(&s_cnt, 1); if (p < MAXJ - 1) s_srcj[p] = adjp[base + 0]; }
        if (d4.y == 0) { int p = atomicAdd(&s_cnt, 1); if (p < MAXJ - 1) s_srcj[p] = adjp[base + 1]; }
        if (d4.z == 0) { int p = atomicAdd(&s_cnt, 1); if (p < MAXJ - 1) s_srcj[p] = adjp[base + 2]; }
        if (d4.w == 0) { int p = atomicAdd(&s_cnt, 1); if (p < MAXJ - 1) s_srcj[p] = adjp[base + 3]; }
    }
    __syncthreads();
    if (tid == 0) {
        int c = s_cnt; if (c > MAXJ - 1) c = MAXJ - 1;
        s_srcj[c] = 0;            // self-loop 0 -> 0; center row is LAST
        s_cnt = c + 1;
    }
    __syncthreads();
    const int cnt = s_cnt;
    const int* nodes = l ? nn2 : nn1;
    if (tid < cnt) s_gid[tid] = nodes[b * Nn + s_srcj[tid]];
    __syncthreads();
    for (int idx = tid; idx < cnt * 32; idx += 256) {
        int j = idx >> 5, k4 = (idx & 31) * 4;
        long gid = s_gid[j];
        float4 f;
        if (f32) {
            f = ((const float4*)emb)[gid * 32 + (k4 >> 2)];
        } else {
            ushort4 u = *(const ushort4*)((const unsigned short*)emb + gid * Dd + k4);
            f.x = bf2f(u.x); f.y = bf2f(u.y); f.z = bf2f(u.z); f.w = bf2f(u.w);
        }
        *(float4*)&s_rows[j * RS + k4] = f;
    }

    grid.sync();    // wv/bdot now globally visible (device-scope rel/acq)

    // ---- Phase 2: stage this layer's 12 wv rows (plain float4 loads).
    for (int i = tid; i < 12 * Dd / 4; i += 256) {
        float4 f = ((const float4*)(wvg + l * 12 * Dd))[i];
        int el = i * 4, row = el >> 7, k = el & 127;
        *(float4*)&s_wv[row * RS + k] = f;
    }
    if (tid == 0) s_bd = wvg[3072 + l];
    __syncthreads();

    // Dots: per row j: (asrc, pm) per head; + adst of center per head.
    const int ntask = cnt * 8 + Hh;
    for (int task = tid; task < ntask; task += 256) {
        int j, h, t;
        if (task < cnt * 8) {
            j = task >> 3; h = (task >> 1) & 3; t = (task & 1) ? 2 : 0;
        } else {
            h = task - cnt * 8; t = 1; j = cnt - 1;   // center row
        }
        const float* wrow = s_wv + (t * 4 + h) * RS;
        const float* row  = s_rows + j * RS;
        float acc = 0.f;
        #pragma unroll 8
        for (int k = 0; k < Dd; ++k) acc += row[k] * wrow[k];
        if (task < cnt * 8) {
            if (task & 1) s_pm[j * Hh + h] = acc;
            else          s_ps[j * Hh + h] = acc;
        } else {
            s_pd[h] = acc;
        }
    }
    __syncthreads();

    // Per-head leaky-relu + softmax over in-edges + weighted sum.
    if (tid < Hh) {
        float pd = s_pd[tid], m = -1e30f;
        for (int j = 0; j < cnt; ++j) {
            float e = s_ps[j * Hh + tid] + pd;
            e = (e >= 0.f) ? e : 0.2f * e;      // leaky relu, slope 0.2
            s_ps[j * Hh + tid] = e;
            if (e > m) m = e;
        }
        float den = 0.f, num = 0.f;
        for (int j = 0; j < cnt; ++j) {
            float ex = expf(s_ps[j * Hh + tid] - m);
            den += ex;
            num += ex * s_pm[j * Hh + tid];
        }
        s_hval[tid] = num / den;
    }
    __syncthreads();
    if (tid == 0)
        partial[x] = 0.25f * (s_hval[0] + s_hval[1] + s_hval[2] + s_hval[3]) + s_bd;

    grid.sync();    // partial globally visible

    // ---- Phase 3: combine pair -> out.
    if (x < Bg && tid == 0) {
        float r = partial[b] + partial[Bg + b];
        if (f32) ((float*)out)[b] = r;
        else     ((__hip_bfloat16*)out)[b] = __float2bfloat16(r);
    }
}

extern "C" void kernel_launch(void* const* d_in, const int* in_sizes, int n_in,
                              void* d_out, int out_size, void* d_ws, size_t ws_size,
                              hipStream_t stream) {
    const int* nn1  = (const int*)d_in[0];
    const int* nn2  = (const int*)d_in[1];
    const int* adj1 = (const int*)d_in[2];
    const int* adj2 = (const int*)d_in[3];
    const void* emb  = d_in[4];
    const void* W1   = d_in[5];
    const void* as1  = d_in[6];
    const void* ad1  = d_in[7];
    const void* b1   = d_in[8];
    const void* W2   = d_in[9];
    const void* as2  = d_in[10];
    const void* ad2  = d_in[11];
    const void* b2   = d_in[12];
    const void* mlpw = d_in[13];
    const void* mlpb = d_in[14];

    float* wvg     = (float*)d_ws;        // 3074 floats
    float* partial = wvg + 3074;          // 128 floats
    void*  out     = d_out;

    void* args[] = {
        (void*)&nn1, (void*)&nn2, (void*)&adj1, (void*)&adj2,
        (void*)&emb,
        (void*)&W1, (void*)&as1, (void*)&ad1, (void*)&b1,
        (void*)&W2, (void*)&as2, (void*)&ad2, (void*)&b2,
        (void*)&mlpw, (void*)&mlpb,
        (void*)&wvg, (void*)&partial, (void*)&out
    };
    hipLaunchCooperativeKernel((const void*)gat_coop_kernel,
                               dim3(2 * Bg), dim3(256), args, 0, stream);
}

// Round 8
// 117.709 us; speedup vs baseline: 1.4379x; 1.4379x over previous
//
#include <hip/hip_runtime.h>
#include <hip/hip_bf16.h>

// Problem constants (from reference)
#define Bg 64       // graphs
#define Nn 256      // nodes per subgraph
#define Ee 2048     // edges per subgraph
#define Dd 128      // hidden dim
#define Hh 4        // heads
#define MAXJ 40     // cap on in-edges of node 0 (+self) per layer; Binom(2048,1/256): P(>38)~1e-17
#define RS 132      // LDS row stride (128 + 4 pad)

__device__ __forceinline__ float bf2f(unsigned short u) {
    return __uint_as_float(((unsigned)u) << 16);
}

// ---------------------------------------------------------------------------
// ONE dispatch, 64 blocks x 1024 threads (16 waves/CU for latency hiding).
// Each block handles one graph, BOTH layers, zero cross-block traffic.
// The wv fold is redundantly recomputed per block, but now one slice (l,h)
// per 128-thread group: per-thread load depth 128 (vs 512 in round 6) and
// 16 resident waves hide the strided W-load latency.
//   wv row r=((l*3+t)*4+h): wv[r][k] = sum_d av_t[d] * W_l[h*Dd+d, k]
//     t: 0=att_src, 1=att_dst, 2=mlp half
// ---------------------------------------------------------------------------
__global__ __launch_bounds__(1024) void gat_fused_kernel(
    const int* nn1, const int* nn2, const int* adj1, const int* adj2,
    const void* emb,
    const void* W1, const void* as1, const void* ad1, const void* b1,
    const void* W2, const void* as2, const void* ad2, const void* b2,
    const void* mlpw, const void* mlpb, void* out)
{
    __shared__ float s_wv[24 * RS];            // 12.7 KB
    __shared__ float s_rows[2 * MAXJ * RS];    // 42.2 KB
    __shared__ float s_red4[4];                // per-wave bdot partials
    __shared__ int   s_srcj[2][MAXJ];
    __shared__ int   s_gid[2 * MAXJ];
    __shared__ int   s_cnt[2];
    __shared__ int   s_f32;
    __shared__ float s_ps[2 * MAXJ * Hh], s_pm[2 * MAXJ * Hh];
    __shared__ float s_pd[2 * Hh], s_hval[2 * Hh], s_bdot[2];

    const int tid = threadIdx.x;
    const int b = blockIdx.x;

    if (tid == 0) { s_f32 = 0; s_cnt[0] = 0; s_cnt[1] = 0; }
    __syncthreads();

    // ---- dtype probe (threads 0..127): fp32 read as bf16 halfwords gives
    // |x|>64 or NaN w.p. ~0.5 per low halfword; bf16 weights are |x| < 0.3.
    // Wave-ballot -> at most 2 LDS atomics.
    if (tid < 128) {
        float v = bf2f(((const unsigned short*)W1)[tid]);
        bool bad = !(v > -64.f && v < 64.f);
        if (__any(bad) && (tid & 63) == 0) atomicOr(&s_f32, 1);
    }
    __syncthreads();
    const int f32 = s_f32;

    // ---- Edge scan, both layers: exactly one int4 per thread.
    {
        const int l = tid >> 9, i = tid & 511;
        const int* adjp = (l ? adj2 : adj1) + (long)b * 2 * Ee;
        int4 d4 = ((const int4*)(adjp + Ee))[i];
        int base = i * 4;
        if (d4.x == 0) { int p = atomicAdd(&s_cnt[l], 1); if (p < MAXJ - 1) s_srcj[l][p] = adjp[base + 0]; }
        if (d4.y == 0) { int p = atomicAdd(&s_cnt[l], 1); if (p < MAXJ - 1) s_srcj[l][p] = adjp[base + 1]; }
        if (d4.z == 0) { int p = atomicAdd(&s_cnt[l], 1); if (p < MAXJ - 1) s_srcj[l][p] = adjp[base + 2]; }
        if (d4.w == 0) { int p = atomicAdd(&s_cnt[l], 1); if (p < MAXJ - 1) s_srcj[l][p] = adjp[base + 3]; }
    }

    // ---- wv fold: slice s = tid>>7 -> (l = s>>2, h = s&3); col k = tid&127.
    // One W column stream feeds 3 accumulators (src/dst/mlp).
    {
        const int s = tid >> 7;
        const int k = tid & 127;
        const int l = s >> 2;
        const int h = s & 3;
        const void* Wp  = l ? W2 : W1;
        const void* asp = l ? as2 : as1;
        const void* adp = l ? ad2 : ad1;
        float a0 = 0.f, a1 = 0.f, a2 = 0.f;
        if (f32) {
            const float* Wf = (const float*)Wp + (long)h * Dd * Dd + k;
            const float* pa = (const float*)asp + h * Dd;
            const float* pb = (const float*)adp + h * Dd;
            const float* pm = (const float*)mlpw + l * Dd;
            #pragma unroll 8
            for (int d = 0; d < Dd; ++d) {
                float w = Wf[(long)d * Dd];
                a0 += pa[d] * w; a1 += pb[d] * w; a2 += pm[d] * w;
            }
        } else {
            const unsigned short* Wb = (const unsigned short*)Wp + (long)h * Dd * Dd + k;
            const unsigned short* pa = (const unsigned short*)asp + h * Dd;
            const unsigned short* pb = (const unsigned short*)adp + h * Dd;
            const unsigned short* pm = (const unsigned short*)mlpw + l * Dd;
            #pragma unroll 8
            for (int d = 0; d < Dd; ++d) {
                float w = bf2f(Wb[(long)d * Dd]);
                a0 += bf2f(pa[d]) * w; a1 += bf2f(pb[d]) * w; a2 += bf2f(pm[d]) * w;
            }
        }
        s_wv[((l * 3 + 0) * 4 + h) * RS + k] = a0;
        s_wv[((l * 3 + 1) * 4 + h) * RS + k] = a1;
        s_wv[((l * 3 + 2) * 4 + h) * RS + k] = a2;
    }

    // ---- bdot partials (threads 0..255): wave-shuffle reduce, no barriers.
    if (tid < 256) {
        const int l = tid >> 7, d = tid & 127;
        const void* bias = l ? b2 : b1;
        float bv, mv;
        if (f32) {
            bv = ((const float*)bias)[d];
            mv = ((const float*)mlpw)[l * Dd + d];
        } else {
            bv = bf2f(((const unsigned short*)bias)[d]);
            mv = bf2f(((const unsigned short*)mlpw)[l * Dd + d]);
        }
        float p = bv * mv;
        #pragma unroll
        for (int off = 32; off > 0; off >>= 1) p += __shfl_down(p, off);
        if ((tid & 63) == 0) s_red4[tid >> 6] = p;
    }
    __syncthreads();     // finalizes: scan counts, s_wv, s_red4

    // ---- bdot combine + self-loop append (thread l = 0,1).
    if (tid < 2) {
        float a = s_red4[2 * tid] + s_red4[2 * tid + 1];
        if (tid == 0)
            a += f32 ? ((const float*)mlpb)[0]
                     : bf2f(((const unsigned short*)mlpb)[0]);
        s_bdot[tid] = a;
        int c = s_cnt[tid];
        if (c > MAXJ - 1) c = MAXJ - 1;
        s_srcj[tid][c] = 0;          // self-loop 0 -> 0; center row is LAST
        s_cnt[tid] = c + 1;
    }
    __syncthreads();
    const int cnt0 = s_cnt[0], cnt1 = s_cnt[1];
    const int tot = cnt0 + cnt1;

    // ---- vocab ids; layer-1 rows appended after layer-0 rows (global j).
    if (tid < 2 * MAXJ) {
        int l = tid / MAXJ, j = tid % MAXJ;
        int cl = l ? cnt1 : cnt0;
        if (j < cl) {
            const int* nodes = l ? nn2 : nn1;
            s_gid[l ? (cnt0 + j) : j] = nodes[b * Nn + s_srcj[l][j]];
        }
    }
    __syncthreads();

    // ---- gather embedding rows (float4/ushort4).
    for (int idx = tid; idx < tot * 32; idx += 1024) {
        int j = idx >> 5, k4 = (idx & 31) * 4;
        long gid = s_gid[j];
        float4 f;
        if (f32) {
            f = ((const float4*)emb)[gid * 32 + (k4 >> 2)];
        } else {
            ushort4 u = *(const ushort4*)((const unsigned short*)emb + gid * Dd + k4);
            f.x = bf2f(u.x); f.y = bf2f(u.y); f.z = bf2f(u.z); f.w = bf2f(u.w);
        }
        *(float4*)&s_rows[j * RS + k4] = f;
    }
    __syncthreads();

    // ---- dots: per global row j: (asrc, pm) per head; + (l,h) center adst.
    const int ntask = tot * 8 + 8;
    for (int task = tid; task < ntask; task += 1024) {
        int j, h, t, l;
        if (task < tot * 8) {
            j = task >> 3; h = (task >> 1) & 3; t = (task & 1) ? 2 : 0;
            l = (j < cnt0) ? 0 : 1;
        } else {
            int z = task - tot * 8;       // 0..7
            l = z >> 2; h = z & 3; t = 1;
            j = l ? (tot - 1) : (cnt0 - 1);   // self-loop row = center node
        }
        const float* wrow = s_wv + ((l * 3 + t) * 4 + h) * RS;
        const float* row  = s_rows + j * RS;
        float acc = 0.f;
        #pragma unroll 8
        for (int k = 0; k < Dd; ++k) acc += row[k] * wrow[k];
        if (task < tot * 8) {
            if (task & 1) s_pm[j * Hh + h] = acc;
            else          s_ps[j * Hh + h] = acc;
        } else {
            s_pd[(l << 2) | h] = acc;
        }
    }
    __syncthreads();

    // ---- per (layer, head): leaky-relu + softmax + weighted sum.
    if (tid < 8) {
        int l = tid >> 2, h = tid & 3;
        int j0 = l ? cnt0 : 0;
        int j1 = l ? tot : cnt0;
        float pd = s_pd[tid], m = -1e30f;
        for (int j = j0; j < j1; ++j) {
            float e = s_ps[j * Hh + h] + pd;
            e = (e >= 0.f) ? e : 0.2f * e;        // leaky relu, slope 0.2
            s_ps[j * Hh + h] = e;
            if (e > m) m = e;
        }
        float den = 0.f, num = 0.f;
        for (int j = j0; j < j1; ++j) {
            float ex = expf(s_ps[j * Hh + h] - m);
            den += ex;
            num += ex * s_pm[j * Hh + h];
        }
        s_hval[tid] = num / den;
    }
    __syncthreads();
    if (tid == 0) {
        float r = 0.25f * (s_hval[0] + s_hval[1] + s_hval[2] + s_hval[3]) + s_bdot[0]
                + 0.25f * (s_hval[4] + s_hval[5] + s_hval[6] + s_hval[7]) + s_bdot[1];
        if (f32) ((float*)out)[b] = r;
        else     ((__hip_bfloat16*)out)[b] = __float2bfloat16(r);
    }
}

extern "C" void kernel_launch(void* const* d_in, const int* in_sizes, int n_in,
                              void* d_out, int out_size, void* d_ws, size_t ws_size,
                              hipStream_t stream) {
    const int* nn1  = (const int*)d_in[0];
    const int* nn2  = (const int*)d_in[1];
    const int* adj1 = (const int*)d_in[2];
    const int* adj2 = (const int*)d_in[3];

    gat_fused_kernel<<<Bg, 1024, 0, stream>>>(
        nn1, nn2, adj1, adj2,
        d_in[4],  /* emb  */
        d_in[5],  /* W1  */ d_in[6],  /* as1 */ d_in[7],  /* ad1 */
        d_in[8],  /* b1  */
        d_in[9],  /* W2  */ d_in[10], /* as2 */ d_in[11], /* ad2 */
        d_in[12], /* b2  */
        d_in[13], /* mlpw */ d_in[14], /* mlpb */
        d_out);
}

// Round 9
// 104.945 us; speedup vs baseline: 1.6127x; 1.1216x over previous
//
#include <hip/hip_runtime.h>
#include <hip/hip_bf16.h>

// Problem constants (from reference)
#define Bg 64       // graphs
#define Nn 256      // nodes per subgraph
#define Ee 2048     // edges per subgraph
#define Dd 128      // hidden dim
#define Hh 4        // heads
#define MAXJ 40     // cap on in-edges of node 0 (+self) per layer; Binom(2048,1/256): P(>38)~1e-17
#define RS 132      // LDS row stride (128 + 4 pad)

__device__ __forceinline__ float bf2f(unsigned short u) {
    return __uint_as_float(((unsigned)u) << 16);
}

// ---------------------------------------------------------------------------
// Kernel 1: wv fold + bdot, with fully COALESCED W reads.
// Grid: 8 blocks = (l = x>>2, h = x&3), 256 threads.
// Thread (kc = (tid&31)*4 cols, dg = tid>>5) accumulates d in [dg*16,dg*16+16)
// with 16 independent float4 row-reads (one memory round trip), 12 accs
// (3 vectors x 4 cols), then LDS combine across the 8 d-groups.
//   wv[((l*3+t)*4+h)*128 + k] = sum_d av_t[d] * W_l[h*128+d, k]
//     t: 0=att_src, 1=att_dst, 2=mlp half.  wv[3072+l] = bdot_l.
// ---------------------------------------------------------------------------
__global__ __launch_bounds__(256) void precompute_kernel(
    const void* W1, const void* as1, const void* ad1, const void* b1,
    const void* W2, const void* as2, const void* ad2, const void* b2,
    const void* mlpw, const void* mlpb, float* wv)
{
    __shared__ float s_av[3 * Dd];         // [t][d]
    __shared__ float s_part[8 * 3 * Dd];   // [dg][t][k]  12 KB
    __shared__ float s_red[2];
    __shared__ int   s_f32;

    const int tid = threadIdx.x;
    const int x = blockIdx.x;
    const int l = x >> 2, h = x & 3;

    // dtype probe: fp32 read as bf16 halfwords -> |x|>64 or NaN w.p. ~0.5 per
    // low halfword (32 of 64 probed); true bf16 weights are all |x| < 0.3.
    if (tid < 64) {
        float v = bf2f(((const unsigned short*)W1)[tid]);
        bool bad = !(v > -64.f && v < 64.f);
        unsigned long long m = __ballot(bad);
        if (tid == 0) s_f32 = (m != 0ull) ? 1 : 0;
    }
    __syncthreads();
    const int f32 = s_f32;

    // stage the 3 attention vectors for this (l,h)
    for (int i = tid; i < 3 * Dd; i += 256) {
        int t = i >> 7, d = i & 127;
        const void* p; long off;
        if (t == 0)      { p = l ? as2 : as1; off = (long)h * Dd + d; }
        else if (t == 1) { p = l ? ad2 : ad1; off = (long)h * Dd + d; }
        else             { p = mlpw;          off = (long)l * Dd + d; }
        s_av[i] = f32 ? ((const float*)p)[off]
                      : bf2f(((const unsigned short*)p)[off]);
    }
    __syncthreads();

    // coalesced fold
    {
        const int kc = (tid & 31) * 4;
        const int d0 = (tid >> 5) * 16;
        float acc[3][4] = {};
        if (f32) {
            const float* Wf = (const float*)(l ? W2 : W1) + (long)h * Dd * Dd;
            #pragma unroll
            for (int dd = 0; dd < 16; ++dd) {
                int d = d0 + dd;
                float4 w = *(const float4*)(Wf + (long)d * Dd + kc);
                #pragma unroll
                for (int t = 0; t < 3; ++t) {
                    float a = s_av[t * Dd + d];
                    acc[t][0] += a * w.x; acc[t][1] += a * w.y;
                    acc[t][2] += a * w.z; acc[t][3] += a * w.w;
                }
            }
        } else {
            const unsigned short* Wb =
                (const unsigned short*)(l ? W2 : W1) + (long)h * Dd * Dd;
            #pragma unroll
            for (int dd = 0; dd < 16; ++dd) {
                int d = d0 + dd;
                ushort4 u = *(const ushort4*)(Wb + (long)d * Dd + kc);
                float wx = bf2f(u.x), wy = bf2f(u.y);
                float wz = bf2f(u.z), ww = bf2f(u.w);
                #pragma unroll
                for (int t = 0; t < 3; ++t) {
                    float a = s_av[t * Dd + d];
                    acc[t][0] += a * wx; acc[t][1] += a * wy;
                    acc[t][2] += a * wz; acc[t][3] += a * ww;
                }
            }
        }
        const int dg = tid >> 5;
        #pragma unroll
        for (int t = 0; t < 3; ++t)
            *(float4*)&s_part[(dg * 3 + t) * Dd + kc] =
                make_float4(acc[t][0], acc[t][1], acc[t][2], acc[t][3]);
    }
    __syncthreads();

    // combine 8 d-groups -> 3 wv rows of this (l,h)
    for (int i = tid; i < 3 * Dd; i += 256) {
        int t = i >> 7, k = i & 127;
        float s = 0.f;
        #pragma unroll
        for (int g = 0; g < 8; ++g) s += s_part[(g * 3 + t) * Dd + k];
        wv[((l * 3 + t) * 4 + h) * Dd + k] = s;
    }

    // bdot (blocks h==0): dot(bias_l, mlp_half_l) (+ mlp_b for l==0)
    if (h == 0) {
        float p = 0.f;
        if (tid < 128) {
            const void* bias = l ? b2 : b1;
            float bv = f32 ? ((const float*)bias)[tid]
                           : bf2f(((const unsigned short*)bias)[tid]);
            p = bv * s_av[2 * Dd + tid];
        }
        #pragma unroll
        for (int off = 32; off > 0; off >>= 1) p += __shfl_down(p, off);
        if (tid == 0 || tid == 64) s_red[tid >> 6] = p;
        __syncthreads();
        if (tid == 0) {
            float a = s_red[0] + s_red[1];
            if (l == 0) a += f32 ? ((const float*)mlpb)[0]
                                 : bf2f(((const unsigned short*)mlpb)[0]);
            wv[3072 + l] = a;
        }
    }
}

// ---------------------------------------------------------------------------
// Kernel 2: one block per graph, both layers, 512 threads.
// Node-id table preloaded into LDS concurrently with the edge scan, so the
// dependent chain is scan -> (LDS lookup) -> emb gather (one HBM trip saved).
// ---------------------------------------------------------------------------
__global__ __launch_bounds__(512) void gat_main_kernel(
    const int* nn1, const int* nn2, const int* adj1, const int* adj2,
    const void* emb, const void* W1, const float* wv, void* out)
{
    __shared__ float s_wv[24 * RS];            // 12.7 KB
    __shared__ float s_rows[2 * MAXJ * RS];    // 42.2 KB
    __shared__ int   s_nodes[2][Nn];           // 2 KB
    __shared__ int   s_srcj[2][MAXJ];
    __shared__ int   s_gid[2 * MAXJ];
    __shared__ int   s_cnt[2];
    __shared__ int   s_f32;
    __shared__ float s_ps[2 * MAXJ * Hh], s_pm[2 * MAXJ * Hh];
    __shared__ float s_pd[2 * Hh], s_hval[2 * Hh], s_bdot[2];

    const int tid = threadIdx.x;
    const int b = blockIdx.x;

    if (tid == 0) { s_cnt[0] = 0; s_cnt[1] = 0; }
    if (tid < 64) {
        float v = bf2f(((const unsigned short*)W1)[tid]);
        bool bad = !(v > -64.f && v < 64.f);
        unsigned long long m = __ballot(bad);
        if (tid == 0) s_f32 = (m != 0ull) ? 1 : 0;
    }
    __syncthreads();
    const int f32 = s_f32;

    // edge scan (2 iters of int4) — the head of the critical chain
    for (int v = tid; v < 2 * (Ee / 4); v += 512) {
        int l = v >> 9, i = v & 511;
        const int* adjp = (l ? adj2 : adj1) + (long)b * 2 * Ee;
        int4 d4 = ((const int4*)(adjp + Ee))[i];
        int base = i * 4;
        if (d4.x == 0) { int p = atomicAdd(&s_cnt[l], 1); if (p < MAXJ - 1) s_srcj[l][p] = adjp[base + 0]; }
        if (d4.y == 0) { int p = atomicAdd(&s_cnt[l], 1); if (p < MAXJ - 1) s_srcj[l][p] = adjp[base + 1]; }
        if (d4.z == 0) { int p = atomicAdd(&s_cnt[l], 1); if (p < MAXJ - 1) s_srcj[l][p] = adjp[base + 2]; }
        if (d4.w == 0) { int p = atomicAdd(&s_cnt[l], 1); if (p < MAXJ - 1) s_srcj[l][p] = adjp[base + 3]; }
    }
    // node-id preload (1 iter, independent of scan)
    {
        int l = tid >> 8, n = tid & 255;
        s_nodes[l][n] = (l ? nn2 : nn1)[b * Nn + n];
    }
    // wv stage (768 float4 / 512 threads = 2 iters) + bdot
    for (int i = tid; i < 768; i += 512) {
        float4 f = ((const float4*)wv)[i];
        int el = i * 4, row = el >> 7, k = el & 127;
        *(float4*)&s_wv[row * RS + k] = f;
    }
    if (tid < 2) s_bdot[tid] = wv[3072 + tid];
    __syncthreads();

    if (tid < 2) {                       // append self-loop (0 -> 0), row LAST
        int c = s_cnt[tid];
        if (c > MAXJ - 1) c = MAXJ - 1;
        s_srcj[tid][c] = 0;
        s_cnt[tid] = c + 1;
    }
    __syncthreads();
    const int cnt0 = s_cnt[0], cnt1 = s_cnt[1];
    const int tot = cnt0 + cnt1;

    // vocab ids via LDS table; layer-1 rows appended after layer-0 rows
    if (tid < 2 * MAXJ) {
        int l = tid / MAXJ, j = tid % MAXJ;
        int cl = l ? cnt1 : cnt0;
        if (j < cl) s_gid[l ? (cnt0 + j) : j] = s_nodes[l][s_srcj[l][j]];
    }
    __syncthreads();

    // gather embedding rows
    if (f32) {
        for (int idx = tid; idx < tot * 32; idx += 512) {
            int j = idx >> 5, k4 = (idx & 31) << 2;
            long gid = s_gid[j];
            float4 f = ((const float4*)emb)[gid * 32 + (k4 >> 2)];
            *(float4*)&s_rows[j * RS + k4] = f;
        }
    } else {
        for (int idx = tid; idx < tot * 16; idx += 512) {
            int j = idx >> 4, k8 = (idx & 15) << 3;
            long gid = s_gid[j];
            uint4 u = *(const uint4*)((const unsigned short*)emb + gid * Dd + k8);
            float4 f0 = make_float4(bf2f(u.x & 0xffff), bf2f(u.x >> 16),
                                    bf2f(u.y & 0xffff), bf2f(u.y >> 16));
            float4 f1 = make_float4(bf2f(u.z & 0xffff), bf2f(u.z >> 16),
                                    bf2f(u.w & 0xffff), bf2f(u.w >> 16));
            *(float4*)&s_rows[j * RS + k8] = f0;
            *(float4*)&s_rows[j * RS + k8 + 4] = f1;
        }
    }
    __syncthreads();

    // dots: per global row j: (asrc, pm) per head; + per (l,h): adst of center
    const int ntask = tot * 8 + 8;
    for (int task = tid; task < ntask; task += 512) {
        int j, h, t, l;
        if (task < tot * 8) {
            j = task >> 3; h = (task >> 1) & 3; t = (task & 1) ? 2 : 0;
            l = (j < cnt0) ? 0 : 1;
        } else {
            int z = task - tot * 8;       // 0..7
            l = z >> 2; h = z & 3; t = 1;
            j = l ? (tot - 1) : (cnt0 - 1);   // self-loop row = center node
        }
        const float* wrow = s_wv + ((l * 3 + t) * 4 + h) * RS;
        const float* row  = s_rows + j * RS;
        float acc = 0.f;
        #pragma unroll 8
        for (int k = 0; k < Dd; ++k) acc += row[k] * wrow[k];
        if (task < tot * 8) {
            if (task & 1) s_pm[j * Hh + h] = acc;
            else          s_ps[j * Hh + h] = acc;
        } else {
            s_pd[(l << 2) | h] = acc;
        }
    }
    __syncthreads();

    // per (layer, head): leaky-relu + softmax over in-edges + weighted sum
    if (tid < 8) {
        int l = tid >> 2, h = tid & 3;
        int j0 = l ? cnt0 : 0;
        int j1 = l ? tot : cnt0;
        float pd = s_pd[tid], m = -1e30f;
        for (int j = j0; j < j1; ++j) {
            float e = s_ps[j * Hh + h] + pd;
            e = (e >= 0.f) ? e : 0.2f * e;        // leaky relu, slope 0.2
            s_ps[j * Hh + h] = e;
            if (e > m) m = e;
        }
        float den = 0.f, num = 0.f;
        for (int j = j0; j < j1; ++j) {
            float ex = expf(s_ps[j * Hh + h] - m);
            den += ex;
            num += ex * s_pm[j * Hh + h];
        }
        s_hval[tid] = num / den;
    }
    __syncthreads();
    if (tid == 0) {
        float r = 0.25f * (s_hval[0] + s_hval[1] + s_hval[2] + s_hval[3]) + s_bdot[0]
                + 0.25f * (s_hval[4] + s_hval[5] + s_hval[6] + s_hval[7]) + s_bdot[1];
        if (f32) ((float*)out)[b] = r;
        else     ((__hip_bfloat16*)out)[b] = __float2bfloat16(r);
    }
}

extern "C" void kernel_launch(void* const* d_in, const int* in_sizes, int n_in,
                              void* d_out, int out_size, void* d_ws, size_t ws_size,
                              hipStream_t stream) {
    const int* nn1  = (const int*)d_in[0];
    const int* nn2  = (const int*)d_in[1];
    const int* adj1 = (const int*)d_in[2];
    const int* adj2 = (const int*)d_in[3];
    float* wv = (float*)d_ws;     // 3074 fp32

    precompute_kernel<<<8, 256, 0, stream>>>(
        d_in[5],  /* W1  */ d_in[6],  /* as1 */ d_in[7],  /* ad1 */
        d_in[8],  /* b1  */
        d_in[9],  /* W2  */ d_in[10], /* as2 */ d_in[11], /* ad2 */
        d_in[12], /* b2  */
        d_in[13], /* mlpw */ d_in[14], /* mlpb */ wv);

    gat_main_kernel<<<Bg, 512, 0, stream>>>(
        nn1, nn2, adj1, adj2, d_in[4] /* emb */, d_in[5] /* W1 */, wv, d_out);
}